// Round 3
// baseline (4846.954 us; speedup 1.0000x reference)
//
#include <hip/hip_runtime.h>
#include <hip/hip_bf16.h>

constexpr int CB = 2, CS = 512, CD = 1024, CH = 16, CHD = 64;
constexpr int CST = 2048, CLT = 6144;
constexpr int CKST = 204, CKLT = 614;

__device__ __forceinline__ unsigned monof(float f) {
  unsigned u = __float_as_uint(f);
  return (u & 0x80000000u) ? ~u : (u | 0x80000000u);
}

__device__ __forceinline__ float block_sum_f(float v, float* scratch, int tid) {
#pragma unroll
  for (int o = 32; o > 0; o >>= 1) v += __shfl_down(v, o, 64);
  if ((tid & 63) == 0) scratch[tid >> 6] = v;
  __syncthreads();
  float r = (scratch[0] + scratch[1]) + (scratch[2] + scratch[3]);
  __syncthreads();
  return r;
}
__device__ __forceinline__ int block_sum_i(int v, int* scratch, int tid) {
#pragma unroll
  for (int o = 32; o > 0; o >>= 1) v += __shfl_down(v, o, 64);
  if ((tid & 63) == 0) scratch[tid >> 6] = v;
  __syncthreads();
  int r = (scratch[0] + scratch[1]) + (scratch[2] + scratch[3]);
  __syncthreads();
  return r;
}
__device__ __forceinline__ float block_max_f(float v, float* scratch, int tid) {
#pragma unroll
  for (int o = 32; o > 0; o >>= 1) v = fmaxf(v, __shfl_down(v, o, 64));
  if ((tid & 63) == 0) scratch[tid >> 6] = v;
  __syncthreads();
  float r = fmaxf(fmaxf(scratch[0], scratch[1]), fmaxf(scratch[2], scratch[3]));
  __syncthreads();
  return r;
}

// K0: bank-mix coefficients from importance means
__global__ __launch_bounds__(256) void prep_kernel(
    const float* __restrict__ st_imp, const float* __restrict__ lt_imp,
    float* __restrict__ scal) {
  __shared__ float scr[4];
  int tid = threadIdx.x;
  float s = 0.f, l = 0.f;
  for (int i = tid; i < CST; i += 256) s += st_imp[i];
  for (int i = tid; i < CLT; i += 256) l += lt_imp[i];
  float ssum = block_sum_f(s, scr, tid);
  float lsum = block_sum_f(l, scr, tid);
  if (tid == 0) {
    float sw = 1.f / (1.f + __expf(-(ssum / CST)));
    float lw = 1.f / (1.f + __expf(-(lsum / CLT)));
    float tot = sw + lw;
    scal[0] = sw / tot;
    scal[1] = lw / tot;
  }
}

// K1: Q = X @ Wq + bq. 4 rows/block, 256 threads, each thread owns 4 output cols.
__global__ __launch_bounds__(256) void qproj_kernel(
    const float* __restrict__ X, const float* __restrict__ Wq,
    const float* __restrict__ bq, float* __restrict__ Qout) {
  __shared__ float xs[4][CD];
  int tid = threadIdx.x;
  int row0 = blockIdx.x * 4;
#pragma unroll
  for (int r = 0; r < 4; ++r)
    for (int dd = tid; dd < CD; dd += 256)
      xs[r][dd] = X[(size_t)(row0 + r) * CD + dd];
  __syncthreads();

  float acc[4][4];
#pragma unroll
  for (int r = 0; r < 4; ++r)
#pragma unroll
    for (int j = 0; j < 4; ++j) acc[r][j] = 0.f;

  int j0 = tid * 4;
  for (int dd = 0; dd < CD; dd += 2) {
    float4 w0 = *(const float4*)&Wq[(size_t)dd * CD + j0];
    float4 w1 = *(const float4*)&Wq[(size_t)(dd + 1) * CD + j0];
#pragma unroll
    for (int r = 0; r < 4; ++r) {
      float x0 = xs[r][dd], x1 = xs[r][dd + 1];
      acc[r][0] += x0 * w0.x + x1 * w1.x;
      acc[r][1] += x0 * w0.y + x1 * w1.y;
      acc[r][2] += x0 * w0.z + x1 * w1.z;
      acc[r][3] += x0 * w0.w + x1 * w1.w;
    }
  }
  float4 bb = *(const float4*)&bq[j0];
#pragma unroll
  for (int r = 0; r < 4; ++r) {
    float4 o;
    o.x = acc[r][0] + bb.x;
    o.y = acc[r][1] + bb.y;
    o.z = acc[r][2] + bb.z;
    o.w = acc[r][3] + bb.w;
    *(float4*)&Qout[(size_t)(row0 + r) * CD + j0] = o;
  }
}

// K2: one block per query (b,h,s); scores in dynamic LDS; exact top-k threshold
// via binary search in monotone-uint space; softmax; PV with zero-skip.
__global__ __launch_bounds__(256) void attn_bank_kernel(
    const float* __restrict__ Q, const float* __restrict__ Kp,
    const float* __restrict__ Vp, const float* __restrict__ imp,
    const float* __restrict__ scal, int scal_idx, int M, int kth,
    float* __restrict__ mem_out, int add_to) {
  extern __shared__ float scores[];
  __shared__ float q_lds[CHD];
  __shared__ float fscr[4];
  __shared__ int iscr[4];
  __shared__ float pvred[256];

  int tid = threadIdx.x;
  int idx = blockIdx.x;
  int s = idx & (CS - 1);
  int h = (idx >> 9) & (CH - 1);
  int b = idx >> 13;

  if (tid < CHD) q_lds[tid] = Q[((size_t)(b * CS + s)) * CD + h * CHD + tid];
  __syncthreads();

  const float4* q4 = (const float4*)q_lds;
  float lmax = -1e30f;
  for (int m = tid; m < M; m += 256) {
    const float4* krow = (const float4*)(Kp + (size_t)m * CD + h * CHD);
    float dot = 0.f;
#pragma unroll
    for (int c = 0; c < 16; ++c) {
      float4 k4 = krow[c];
      float4 qa = q4[c];
      dot += k4.x * qa.x + k4.y * qa.y + k4.z * qa.z + k4.w * qa.w;
    }
    float sc = dot * 0.125f * imp[m];
    scores[m] = sc;
    lmax = fmaxf(lmax, sc);
  }
  float gmax = block_max_f(lmax, fscr, tid);  // barrier also publishes scores[]

  // exact k-th largest via binary search on monotone uint mapping
  unsigned lo = 0u, hi = 0xFFFFFFFFu;
  while (lo < hi) {
    unsigned range = hi - lo;
    unsigned mid = lo + (range >> 1) + (range & 1u);  // upper mid, no overflow
    int cnt = 0;
    for (int m = tid; m < M; m += 256) cnt += (monof(scores[m]) >= mid) ? 1 : 0;
    int total = block_sum_i(cnt, iscr, tid);
    if (total >= kth) lo = mid;
    else hi = mid - 1;
  }
  unsigned thr = lo;

  // softmax weights (overwrite scores with weights)
  float wsum = 0.f;
  for (int m = tid; m < M; m += 256) {
    float sc = scores[m];
    float w = (monof(sc) >= thr) ? __expf(sc - gmax) : 0.f;
    scores[m] = w;
    wsum += w;
  }
  float tot = block_sum_f(wsum, fscr, tid);  // barrier publishes weights

  // PV: thread (g,d); g = wave id (wave-uniform weight -> uniform skip)
  int d = tid & 63;
  int g = tid >> 6;
  float acc = 0.f;
  for (int m = g; m < M; m += 4) {
    float w = scores[m];
    if (w != 0.f)
      acc += w * Vp[(size_t)m * CD + h * CHD + d];
  }
  pvred[tid] = acc;
  __syncthreads();
  if (tid < 64) {
    float o = (pvred[tid] + pvred[tid + 64]) + (pvred[tid + 128] + pvred[tid + 192]);
    o = o / tot * scal[scal_idx];
    size_t off = ((size_t)(b * CS + s)) * CD + h * CHD + tid;
    if (add_to) mem_out[off] += o;
    else mem_out[off] = o;
  }
}

// K3: gate + residual + LayerNorm -> fp32 out. One block per (b,s) row.
__global__ __launch_bounds__(256) void gate_ln_kernel(
    const float* __restrict__ X, const float* __restrict__ Mem,
    const float* __restrict__ Wg, const float* __restrict__ bg,
    const float* __restrict__ lng, const float* __restrict__ lnb,
    float* __restrict__ Out) {
  __shared__ float scr[4];
  int tid = threadIdx.x;
  int row = blockIdx.x;
  int d0 = tid * 4;

  float4 px = *(const float4*)(X + (size_t)row * CD + d0);
  float4 pm = *(const float4*)(Mem + (size_t)row * CD + d0);
  float4 wi = *(const float4*)(Wg + d0);
  float4 wm = *(const float4*)(Wg + CD + d0);

  float t = px.x * wi.x + px.y * wi.y + px.z * wi.z + px.w * wi.w +
            pm.x * wm.x + pm.y * wm.y + pm.z * wm.z + pm.w * wm.w;
  float z = block_sum_f(t, scr, tid) + bg[0];
  float gate = 1.f / (1.f + __expf(-z));

  float xr0 = px.x + pm.x * gate;
  float xr1 = px.y + pm.y * gate;
  float xr2 = px.z + pm.z * gate;
  float xr3 = px.w + pm.w * gate;

  float ssum = block_sum_f(xr0 + xr1 + xr2 + xr3, scr, tid);
  float ssq = block_sum_f(xr0 * xr0 + xr1 * xr1 + xr2 * xr2 + xr3 * xr3, scr, tid);
  float mu = ssum * (1.f / CD);
  float var = ssq * (1.f / CD) - mu * mu;
  float inv = rsqrtf(var + 1e-5f);

  float4 pg = *(const float4*)(lng + d0);
  float4 pb = *(const float4*)(lnb + d0);
  float4 o;
  o.x = (xr0 - mu) * inv * pg.x + pb.x;
  o.y = (xr1 - mu) * inv * pg.y + pb.y;
  o.z = (xr2 - mu) * inv * pg.z + pb.z;
  o.w = (xr3 - mu) * inv * pg.w + pb.w;
  *(float4*)(Out + (size_t)row * CD + d0) = o;
}

extern "C" void kernel_launch(void* const* d_in, const int* in_sizes, int n_in,
                              void* d_out, int out_size, void* d_ws, size_t ws_size,
                              hipStream_t stream) {
  const float* inputs = (const float*)d_in[0];
  const float* Wq = (const float*)d_in[1];
  const float* bq = (const float*)d_in[2];
  const float* st_keys = (const float*)d_in[3];
  const float* st_values = (const float*)d_in[4];
  const float* lt_keys = (const float*)d_in[5];
  const float* lt_values = (const float*)d_in[6];
  const float* st_imp = (const float*)d_in[7];
  const float* lt_imp = (const float*)d_in[8];
  const float* Wg = (const float*)d_in[9];
  const float* bg = (const float*)d_in[10];
  const float* ln_g = (const float*)d_in[11];
  const float* ln_b = (const float*)d_in[12];
  float* out = (float*)d_out;

  float* Qws = (float*)d_ws;                       // B*S*D fp32 = 4 MB
  float* Memws = Qws + (size_t)CB * CS * CD;       // B*S*D fp32 = 4 MB
  float* scal = Memws + (size_t)CB * CS * CD;      // 2 fp32

  prep_kernel<<<1, 256, 0, stream>>>(st_imp, lt_imp, scal);
  qproj_kernel<<<CB * CS / 4, 256, 0, stream>>>(inputs, Wq, bq, Qws);
  attn_bank_kernel<<<CB * CH * CS, 256, CST * sizeof(float), stream>>>(
      Qws, st_keys, st_values, st_imp, scal, 0, CST, CKST, Memws, 0);
  attn_bank_kernel<<<CB * CH * CS, 256, CLT * sizeof(float), stream>>>(
      Qws, lt_keys, lt_values, lt_imp, scal, 1, CLT, CKLT, Memws, 1);
  gate_ln_kernel<<<CB * CS, 256, 0, stream>>>(inputs, Memws, Wg, bg, ln_g, ln_b, out);
}

// Round 4
// 2778.893 us; speedup vs baseline: 1.7442x; 1.7442x over previous
//
#include <hip/hip_runtime.h>
#include <hip/hip_bf16.h>

typedef unsigned short ushort_t;

constexpr int CB = 2, CS = 512, CD = 1024, CH = 16, CHD = 64;
constexpr int CST = 2048, CLT = 6144;
constexpr int CKST = 204, CKLT = 614;

__device__ __forceinline__ float bf2f(ushort_t u) {
  return __uint_as_float(((unsigned)u) << 16);
}
__device__ __forceinline__ ushort_t f2bf(float f) {
  __hip_bfloat16 h = __float2bfloat16(f);
  return *reinterpret_cast<ushort_t*>(&h);
}
// monotone 16-bit key: mono(a) > mono(b) <=> bf16 a > b
__device__ __forceinline__ int mono16(ushort_t u) {
  return (u & 0x8000) ? (int)((ushort_t)~u) : (int)(u | 0x8000);
}

__device__ __forceinline__ float block_sum_f(float v, float* scratch, int tid) {
#pragma unroll
  for (int o = 32; o > 0; o >>= 1) v += __shfl_down(v, o, 64);
  if ((tid & 63) == 0) scratch[tid >> 6] = v;
  __syncthreads();
  float r = (scratch[0] + scratch[1]) + (scratch[2] + scratch[3]);
  __syncthreads();
  return r;
}
__device__ __forceinline__ float block_max_f(float v, float* scratch, int tid) {
#pragma unroll
  for (int o = 32; o > 0; o >>= 1) v = fmaxf(v, __shfl_down(v, o, 64));
  if ((tid & 63) == 0) scratch[tid >> 6] = v;
  __syncthreads();
  float r = fmaxf(fmaxf(scratch[0], scratch[1]), fmaxf(scratch[2], scratch[3]));
  __syncthreads();
  return r;
}

// K0: bank-mix coefficients
__global__ __launch_bounds__(256) void prep_kernel(
    const float* __restrict__ st_imp, const float* __restrict__ lt_imp,
    float* __restrict__ scal) {
  __shared__ float scr[4];
  int tid = threadIdx.x;
  float s = 0.f, l = 0.f;
  for (int i = tid; i < CST; i += 256) s += st_imp[i];
  for (int i = tid; i < CLT; i += 256) l += lt_imp[i];
  float ssum = block_sum_f(s, scr, tid);
  float lsum = block_sum_f(l, scr, tid);
  if (tid == 0) {
    float sw = 1.f / (1.f + __expf(-(ssum / CST)));
    float lw = 1.f / (1.f + __expf(-(lsum / CLT)));
    float tot = sw + lw;
    scal[0] = sw / tot;
    scal[1] = lw / tot;
  }
}

// K1: Q = X @ Wq + bq
__global__ __launch_bounds__(256) void qproj_kernel(
    const float* __restrict__ X, const float* __restrict__ Wq,
    const float* __restrict__ bq, float* __restrict__ Qout) {
  __shared__ float xs[4][CD];
  int tid = threadIdx.x;
  int row0 = blockIdx.x * 4;
#pragma unroll
  for (int r = 0; r < 4; ++r)
    for (int dd = tid; dd < CD; dd += 256)
      xs[r][dd] = X[(size_t)(row0 + r) * CD + dd];
  __syncthreads();

  float acc[4][4];
#pragma unroll
  for (int r = 0; r < 4; ++r)
#pragma unroll
    for (int j = 0; j < 4; ++j) acc[r][j] = 0.f;

  int j0 = tid * 4;
  for (int dd = 0; dd < CD; dd += 2) {
    float4 w0 = *(const float4*)&Wq[(size_t)dd * CD + j0];
    float4 w1 = *(const float4*)&Wq[(size_t)(dd + 1) * CD + j0];
#pragma unroll
    for (int r = 0; r < 4; ++r) {
      float x0 = xs[r][dd], x1 = xs[r][dd + 1];
      acc[r][0] += x0 * w0.x + x1 * w1.x;
      acc[r][1] += x0 * w0.y + x1 * w1.y;
      acc[r][2] += x0 * w0.z + x1 * w1.z;
      acc[r][3] += x0 * w0.w + x1 * w1.w;
    }
  }
  float4 bb = *(const float4*)&bq[j0];
#pragma unroll
  for (int r = 0; r < 4; ++r) {
    float4 o;
    o.x = acc[r][0] + bb.x;
    o.y = acc[r][1] + bb.y;
    o.z = acc[r][2] + bb.z;
    o.w = acc[r][3] + bb.w;
    *(float4*)&Qout[(size_t)(row0 + r) * CD + j0] = o;
  }
}

// K2 v2: 4 queries/block (same b,h, consecutive s). bf16 scores in LDS,
// 2-level 256-bucket histogram exact select, compacted index list, PV one
// query per wave over selected rows only.
template <int M, int NPT, int LCAP>
__global__ __launch_bounds__(256) void attn_v2(
    const float* __restrict__ Q, const float* __restrict__ Kp,
    const float* __restrict__ Vp, const float* __restrict__ imp,
    const float* __restrict__ scal, int scal_idx, int kth,
    float* __restrict__ mem_out, int add_to) {
  __shared__ float q_l[4][CHD];
  __shared__ ushort_t sc_l[4][M];
  __shared__ ushort_t il[4][LCAP];
  __shared__ int hist[256];
  __shared__ int hc[256];
  __shared__ float fscr[4];
  __shared__ int iscr[4];
  __shared__ int bsel, ksel;

  int tid = threadIdx.x;
  int idx = blockIdx.x;
  int sg = idx & (CS / 4 - 1);
  int h = (idx >> 7) & (CH - 1);
  int b = idx >> 11;
  int s0 = sg * 4;

  {
    int qi = tid >> 6, d = tid & 63;
    q_l[qi][d] = Q[((size_t)(b * CS + s0 + qi)) * CD + h * CHD + d];
  }
  __syncthreads();

  float lmax0 = -1e30f, lmax1 = -1e30f, lmax2 = -1e30f, lmax3 = -1e30f;

  // ---- phase 1: scores (fp32 compute, bf16 store) ----
  for (int j0 = 0; j0 < NPT; j0 += 2) {
    int m0 = tid + j0 * 256;
    int m1 = m0 + 256;
    float a00 = 0, a01 = 0, a10 = 0, a11 = 0, a20 = 0, a21 = 0, a30 = 0, a31 = 0;
#pragma unroll
    for (int qt = 0; qt < 4; ++qt) {  // quarter of the 64-dim row (16 dims)
      const float4* r0 = (const float4*)(Kp + (size_t)m0 * CD + h * CHD + qt * 16);
      const float4* r1 = (const float4*)(Kp + (size_t)m1 * CD + h * CHD + qt * 16);
      float4 kA[4], kB[4];
#pragma unroll
      for (int c = 0; c < 4; ++c) { kA[c] = r0[c]; kB[c] = r1[c]; }
#pragma unroll
      for (int c = 0; c < 4; ++c) {
        float4 q0 = *(const float4*)&q_l[0][qt * 16 + c * 4];
        float4 q1 = *(const float4*)&q_l[1][qt * 16 + c * 4];
        float4 q2 = *(const float4*)&q_l[2][qt * 16 + c * 4];
        float4 q3 = *(const float4*)&q_l[3][qt * 16 + c * 4];
        a00 += kA[c].x * q0.x + kA[c].y * q0.y + kA[c].z * q0.z + kA[c].w * q0.w;
        a01 += kB[c].x * q0.x + kB[c].y * q0.y + kB[c].z * q0.z + kB[c].w * q0.w;
        a10 += kA[c].x * q1.x + kA[c].y * q1.y + kA[c].z * q1.z + kA[c].w * q1.w;
        a11 += kB[c].x * q1.x + kB[c].y * q1.y + kB[c].z * q1.z + kB[c].w * q1.w;
        a20 += kA[c].x * q2.x + kA[c].y * q2.y + kA[c].z * q2.z + kA[c].w * q2.w;
        a21 += kB[c].x * q2.x + kB[c].y * q2.y + kB[c].z * q2.z + kB[c].w * q2.w;
        a30 += kA[c].x * q3.x + kA[c].y * q3.y + kA[c].z * q3.z + kA[c].w * q3.w;
        a31 += kB[c].x * q3.x + kB[c].y * q3.y + kB[c].z * q3.z + kB[c].w * q3.w;
      }
    }
    float f0 = 0.125f * imp[m0], f1 = 0.125f * imp[m1];
    float s00 = a00 * f0, s01 = a01 * f1;
    float s10 = a10 * f0, s11 = a11 * f1;
    float s20 = a20 * f0, s21 = a21 * f1;
    float s30 = a30 * f0, s31 = a31 * f1;
    sc_l[0][m0] = f2bf(s00); sc_l[0][m1] = f2bf(s01);
    sc_l[1][m0] = f2bf(s10); sc_l[1][m1] = f2bf(s11);
    sc_l[2][m0] = f2bf(s20); sc_l[2][m1] = f2bf(s21);
    sc_l[3][m0] = f2bf(s30); sc_l[3][m1] = f2bf(s31);
    lmax0 = fmaxf(lmax0, fmaxf(s00, s01));
    lmax1 = fmaxf(lmax1, fmaxf(s10, s11));
    lmax2 = fmaxf(lmax2, fmaxf(s20, s21));
    lmax3 = fmaxf(lmax3, fmaxf(s30, s31));
  }

  float gmaxr[4];
  gmaxr[0] = block_max_f(lmax0, fscr, tid);
  gmaxr[1] = block_max_f(lmax1, fscr, tid);
  gmaxr[2] = block_max_f(lmax2, fscr, tid);
  gmaxr[3] = block_max_f(lmax3, fscr, tid);

  float wsumr[4];
  int nselr[4];

  // ---- phase 2: per-query exact select + compact ----
  for (int qi = 0; qi < 4; ++qi) {
    // level-1 histogram on high 8 bits of mono16
    hist[tid] = 0;
    __syncthreads();
#pragma unroll
    for (int j = 0; j < NPT; ++j) {
      ushort_t u = sc_l[qi][tid + j * 256];
      atomicAdd(&hist[mono16(u) >> 8], 1);
    }
    __syncthreads();
    hc[tid] = hist[tid];
    __syncthreads();
#pragma unroll
    for (int off = 1; off < 256; off <<= 1) {
      int add = (tid + off < 256) ? hc[tid + off] : 0;
      __syncthreads();
      hc[tid] += add;
      __syncthreads();
    }
    if (hc[tid] >= kth && (tid == 255 || hc[tid + 1] < kth)) {
      bsel = tid;
      ksel = kth - (tid == 255 ? 0 : hc[tid + 1]);
    }
    __syncthreads();
    int b1 = bsel, kp = ksel;
    __syncthreads();
    // level-2 histogram on low 8 bits within bucket b1
    hist[tid] = 0;
    __syncthreads();
#pragma unroll
    for (int j = 0; j < NPT; ++j) {
      int mn = mono16(sc_l[qi][tid + j * 256]);
      if ((mn >> 8) == b1) atomicAdd(&hist[mn & 0xFF], 1);
    }
    __syncthreads();
    hc[tid] = hist[tid];
    __syncthreads();
#pragma unroll
    for (int off = 1; off < 256; off <<= 1) {
      int add = (tid + off < 256) ? hc[tid + off] : 0;
      __syncthreads();
      hc[tid] += add;
      __syncthreads();
    }
    if (hc[tid] >= kp && (tid == 255 || hc[tid + 1] < kp)) bsel = tid;
    __syncthreads();
    int thr = (b1 << 8) | bsel;
    __syncthreads();

    // count + softmax partial sum over selected
    float gm = gmaxr[qi];
    int cnt = 0;
    float ws = 0.f;
#pragma unroll
    for (int j = 0; j < NPT; ++j) {
      ushort_t u = sc_l[qi][tid + j * 256];
      if (mono16(u) >= thr) {
        cnt++;
        ws += __expf(bf2f(u) - gm);
      }
    }
    // exclusive block scan of cnt -> write position
    int lane = tid & 63, wv = tid >> 6;
    int v = cnt;
#pragma unroll
    for (int off = 1; off < 64; off <<= 1) {
      int t = __shfl_up(v, off, 64);
      if (lane >= off) v += t;
    }
    if (lane == 63) iscr[wv] = v;
    __syncthreads();
    int base = 0;
#pragma unroll
    for (int w = 0; w < 4; ++w)
      if (w < wv) base += iscr[w];
    int pos = base + v - cnt;
    int ntot = iscr[0] + iscr[1] + iscr[2] + iscr[3];
    __syncthreads();
#pragma unroll
    for (int j = 0; j < NPT; ++j) {
      int m = tid + j * 256;
      ushort_t u = sc_l[qi][m];
      if (mono16(u) >= thr) {
        if (pos < LCAP) il[qi][pos] = (ushort_t)m;
        pos++;
      }
    }
    wsumr[qi] = block_sum_f(ws, fscr, tid);
    nselr[qi] = ntot < LCAP ? ntot : LCAP;
    __syncthreads();
  }

  // ---- phase 3: PV, one query per wave, selected rows only ----
  {
    int wv = tid >> 6, d = tid & 63;
    float gm = gmaxr[wv];
    float wsc = scal[scal_idx] / wsumr[wv];
    int n = nselr[wv];
    const float* Vh = Vp + h * CHD + d;
    float acc = 0.f;
    int i = 0;
    for (; i + 4 <= n; i += 4) {
      int m0 = il[wv][i], m1 = il[wv][i + 1], m2 = il[wv][i + 2], m3 = il[wv][i + 3];
      float v0 = Vh[(size_t)m0 * CD];
      float v1 = Vh[(size_t)m1 * CD];
      float v2 = Vh[(size_t)m2 * CD];
      float v3 = Vh[(size_t)m3 * CD];
      float w0 = __expf(bf2f(sc_l[wv][m0]) - gm);
      float w1 = __expf(bf2f(sc_l[wv][m1]) - gm);
      float w2 = __expf(bf2f(sc_l[wv][m2]) - gm);
      float w3 = __expf(bf2f(sc_l[wv][m3]) - gm);
      acc += w0 * v0 + w1 * v1 + w2 * v2 + w3 * v3;
    }
    for (; i < n; ++i) {
      int m0 = il[wv][i];
      acc += __expf(bf2f(sc_l[wv][m0]) - gm) * Vh[(size_t)m0 * CD];
    }
    size_t off = ((size_t)(b * CS + s0 + wv)) * CD + h * CHD + d;
    float o = acc * wsc;
    if (add_to) mem_out[off] += o;
    else mem_out[off] = o;
  }
}

// K3: gate + residual + LayerNorm
__global__ __launch_bounds__(256) void gate_ln_kernel(
    const float* __restrict__ X, const float* __restrict__ Mem,
    const float* __restrict__ Wg, const float* __restrict__ bg,
    const float* __restrict__ lng, const float* __restrict__ lnb,
    float* __restrict__ Out) {
  __shared__ float scr[4];
  int tid = threadIdx.x;
  int row = blockIdx.x;
  int d0 = tid * 4;

  float4 px = *(const float4*)(X + (size_t)row * CD + d0);
  float4 pm = *(const float4*)(Mem + (size_t)row * CD + d0);
  float4 wi = *(const float4*)(Wg + d0);
  float4 wm = *(const float4*)(Wg + CD + d0);

  float t = px.x * wi.x + px.y * wi.y + px.z * wi.z + px.w * wi.w +
            pm.x * wm.x + pm.y * wm.y + pm.z * wm.z + pm.w * wm.w;
  float z = block_sum_f(t, scr, tid) + bg[0];
  float gate = 1.f / (1.f + __expf(-z));

  float xr0 = px.x + pm.x * gate;
  float xr1 = px.y + pm.y * gate;
  float xr2 = px.z + pm.z * gate;
  float xr3 = px.w + pm.w * gate;

  float ssum = block_sum_f(xr0 + xr1 + xr2 + xr3, scr, tid);
  float ssq = block_sum_f(xr0 * xr0 + xr1 * xr1 + xr2 * xr2 + xr3 * xr3, scr, tid);
  float mu = ssum * (1.f / CD);
  float var = ssq * (1.f / CD) - mu * mu;
  float inv = rsqrtf(var + 1e-5f);

  float4 pg = *(const float4*)(lng + d0);
  float4 pb = *(const float4*)(lnb + d0);
  float4 o;
  o.x = (xr0 - mu) * inv * pg.x + pb.x;
  o.y = (xr1 - mu) * inv * pg.y + pb.y;
  o.z = (xr2 - mu) * inv * pg.z + pb.z;
  o.w = (xr3 - mu) * inv * pg.w + pb.w;
  *(float4*)(Out + (size_t)row * CD + d0) = o;
}

extern "C" void kernel_launch(void* const* d_in, const int* in_sizes, int n_in,
                              void* d_out, int out_size, void* d_ws, size_t ws_size,
                              hipStream_t stream) {
  const float* inputs = (const float*)d_in[0];
  const float* Wq = (const float*)d_in[1];
  const float* bq = (const float*)d_in[2];
  const float* st_keys = (const float*)d_in[3];
  const float* st_values = (const float*)d_in[4];
  const float* lt_keys = (const float*)d_in[5];
  const float* lt_values = (const float*)d_in[6];
  const float* st_imp = (const float*)d_in[7];
  const float* lt_imp = (const float*)d_in[8];
  const float* Wg = (const float*)d_in[9];
  const float* bg = (const float*)d_in[10];
  const float* ln_g = (const float*)d_in[11];
  const float* ln_b = (const float*)d_in[12];
  float* out = (float*)d_out;

  float* Qws = (float*)d_ws;                   // B*S*D fp32 = 4 MB
  float* Memws = Qws + (size_t)CB * CS * CD;   // B*S*D fp32 = 4 MB
  float* scal = Memws + (size_t)CB * CS * CD;  // 2 fp32

  int nblk = CB * CH * (CS / 4);  // 4096

  prep_kernel<<<1, 256, 0, stream>>>(st_imp, lt_imp, scal);
  qproj_kernel<<<CB * CS / 4, 256, 0, stream>>>(inputs, Wq, bq, Qws);
  attn_v2<CST, CST / 256, 512><<<nblk, 256, 0, stream>>>(
      Qws, st_keys, st_values, st_imp, scal, 0, CKST, Memws, 0);
  attn_v2<CLT, CLT / 256, 1024><<<nblk, 256, 0, stream>>>(
      Qws, lt_keys, lt_values, lt_imp, scal, 1, CKLT, Memws, 1);
  gate_ln_kernel<<<CB * CS, 256, 0, stream>>>(inputs, Memws, Wg, bg, ln_g, ln_b, out);
}

// Round 5
// 1280.854 us; speedup vs baseline: 3.7842x; 2.1696x over previous
//
#include <hip/hip_runtime.h>
#include <hip/hip_bf16.h>

typedef unsigned short ushort_t;

constexpr int CB = 2, CS = 512, CD = 1024, CH = 16, CHD = 64;
constexpr int CST = 2048, CLT = 6144;
constexpr int CKST = 204, CKLT = 614;

__device__ __forceinline__ float u2f(unsigned u) { return __uint_as_float(u); }
__device__ __forceinline__ float bf2f(ushort_t u) {
  return __uint_as_float(((unsigned)u) << 16);
}
__device__ __forceinline__ ushort_t f2bf(float f) {
  __hip_bfloat16 h = __float2bfloat16(f);
  return *reinterpret_cast<ushort_t*>(&h);
}
// monotone 16-bit key: mono(a) > mono(b) <=> bf16 a > b
__device__ __forceinline__ int mono16(ushort_t u) {
  return (u & 0x8000) ? (int)((ushort_t)~u) : (int)(u | 0x8000);
}

__device__ __forceinline__ float block_sum_f(float v, float* scratch, int tid) {
#pragma unroll
  for (int o = 32; o > 0; o >>= 1) v += __shfl_down(v, o, 64);
  if ((tid & 63) == 0) scratch[tid >> 6] = v;
  __syncthreads();
  float r = (scratch[0] + scratch[1]) + (scratch[2] + scratch[3]);
  __syncthreads();
  return r;
}
__device__ __forceinline__ float block_max_f(float v, float* scratch, int tid) {
#pragma unroll
  for (int o = 32; o > 0; o >>= 1) v = fmaxf(v, __shfl_down(v, o, 64));
  if ((tid & 63) == 0) scratch[tid >> 6] = v;
  __syncthreads();
  float r = fmaxf(fmaxf(scratch[0], scratch[1]), fmaxf(scratch[2], scratch[3]));
  __syncthreads();
  return r;
}

// ---------------- K0: bank-mix coefficients ----------------
__global__ __launch_bounds__(256) void prep_kernel(
    const float* __restrict__ st_imp, const float* __restrict__ lt_imp,
    float* __restrict__ scal) {
  __shared__ float scr[4];
  int tid = threadIdx.x;
  float s = 0.f, l = 0.f;
  for (int i = tid; i < CST; i += 256) s += st_imp[i];
  for (int i = tid; i < CLT; i += 256) l += lt_imp[i];
  float ssum = block_sum_f(s, scr, tid);
  float lsum = block_sum_f(l, scr, tid);
  if (tid == 0) {
    float sw = 1.f / (1.f + __expf(-(ssum / CST)));
    float lw = 1.f / (1.f + __expf(-(lsum / CLT)));
    float tot = sw + lw;
    scal[0] = sw / tot;
    scal[1] = lw / tot;
  }
}

// ---------------- K1: Q = X @ Wq + bq ----------------
__global__ __launch_bounds__(256) void qproj_kernel(
    const float* __restrict__ X, const float* __restrict__ Wq,
    const float* __restrict__ bq, float* __restrict__ Qout) {
  __shared__ float xs[4][CD];
  int tid = threadIdx.x;
  int row0 = blockIdx.x * 4;
#pragma unroll
  for (int r = 0; r < 4; ++r)
    for (int dd = tid; dd < CD; dd += 256)
      xs[r][dd] = X[(size_t)(row0 + r) * CD + dd];
  __syncthreads();

  float acc[4][4];
#pragma unroll
  for (int r = 0; r < 4; ++r)
#pragma unroll
    for (int j = 0; j < 4; ++j) acc[r][j] = 0.f;

  int j0 = tid * 4;
  for (int dd = 0; dd < CD; dd += 2) {
    float4 w0 = *(const float4*)&Wq[(size_t)dd * CD + j0];
    float4 w1 = *(const float4*)&Wq[(size_t)(dd + 1) * CD + j0];
#pragma unroll
    for (int r = 0; r < 4; ++r) {
      float x0 = xs[r][dd], x1 = xs[r][dd + 1];
      acc[r][0] += x0 * w0.x + x1 * w1.x;
      acc[r][1] += x0 * w0.y + x1 * w1.y;
      acc[r][2] += x0 * w0.z + x1 * w1.z;
      acc[r][3] += x0 * w0.w + x1 * w1.w;
    }
  }
  float4 bb = *(const float4*)&bq[j0];
#pragma unroll
  for (int r = 0; r < 4; ++r) {
    float4 o;
    o.x = acc[r][0] + bb.x;
    o.y = acc[r][1] + bb.y;
    o.z = acc[r][2] + bb.z;
    o.w = acc[r][3] + bb.w;
    *(float4*)&Qout[(size_t)(row0 + r) * CD + j0] = o;
  }
}

// ---------------- K-transpose: K[m][h*64+d] (f32) -> KT[(h*64+d)][m] (bf16) ----
template <int M>
__global__ __launch_bounds__(256) void ktrans_kernel(
    const float* __restrict__ K, ushort_t* __restrict__ KT) {
  __shared__ float ts[64][65];
  int tid = threadIdx.x;
  int mt = blockIdx.x % (M / 64);
  int h = blockIdx.x / (M / 64);
  int m0 = mt * 64;

#pragma unroll
  for (int p = 0; p < 4; ++p) {
    int ml = p * 16 + (tid >> 4);
    int dc = (tid & 15) * 4;
    float4 v = *(const float4*)&K[(size_t)(m0 + ml) * CD + h * CHD + dc];
    ts[ml][dc] = v.x; ts[ml][dc + 1] = v.y; ts[ml][dc + 2] = v.z; ts[ml][dc + 3] = v.w;
  }
  __syncthreads();

  int d = tid >> 2;
  int mg = (tid & 3) * 16;
  unsigned pk[8];
#pragma unroll
  for (int i = 0; i < 8; ++i) {
    ushort_t lo = f2bf(ts[mg + 2 * i][d]);
    ushort_t hi = f2bf(ts[mg + 2 * i + 1][d]);
    pk[i] = (unsigned)lo | ((unsigned)hi << 16);
  }
  ushort_t* dst = KT + (size_t)(h * CHD + d) * M + m0 + mg;
  *(uint4*)dst = make_uint4(pk[0], pk[1], pk[2], pk[3]);
  *(uint4*)(dst + 8) = make_uint4(pk[4], pk[5], pk[6], pk[7]);
}

// wave-level select helper: given 256-bin histogram (histw), find largest bin
// with suffix-count >= kk; returns (bin, remaining k within bin).
__device__ __forceinline__ int2 wave_hist_select(const int* histw, int l, int kk) {
  int4 c = *(const int4*)&histw[4 * l];
  int suf = c.x + c.y + c.z + c.w;
#pragma unroll
  for (int off = 1; off < 64; off <<= 1) {
    int t = __shfl_down(suf, off, 64);
    suf += (l + off < 64) ? t : 0;
  }
  unsigned long long bal = __ballot(suf >= kk);
  int L = 63 - __builtin_clzll(bal);
  int snL = __shfl(suf, (L + 1) & 63, 64);
  int sufL1 = (L == 63) ? 0 : snL;
  int cy = __shfl(c.y, L, 64);
  int cz = __shfl(c.z, L, 64);
  int cw = __shfl(c.w, L, 64);
  int s3 = cw + sufL1, s2 = cz + s3, s1 = cy + s2;
  int bin, rem;
  if (s3 >= kk)      { bin = 4 * L + 3; rem = kk - sufL1; }
  else if (s2 >= kk) { bin = 4 * L + 2; rem = kk - s3; }
  else if (s1 >= kk) { bin = 4 * L + 1; rem = kk - s2; }
  else               { bin = 4 * L;     rem = kk - s1; }
  return make_int2(bin, rem);
}

// ---------------- K2 v3: coalesced KT scores + wave-per-query select + PV ----
// 4 queries/block; wave w owns query w for select & PV. NG = M/2048.
template <int M, int LCAP, int NG>
__global__ __launch_bounds__(256) void attn_v3(
    const float* __restrict__ Q, const ushort_t* __restrict__ KT,
    const float* __restrict__ Vp, const float* __restrict__ imp,
    const float* __restrict__ scal, int scal_idx, int kth,
    float* __restrict__ mem_out, int add_to) {
  __shared__ ushort_t sc_l[4][M];
  __shared__ ushort_t il[4][LCAP];
  __shared__ int hist[4][256];
  __shared__ float q_l[4][CHD];
  __shared__ float wmax[4][4];  // [wave][query]

  int tid = threadIdx.x;
  int l = tid & 63;
  int wv = tid >> 6;
  int idx = blockIdx.x;
  int sg = idx & (CS / 4 - 1);
  int h = (idx >> 7) & (CH - 1);
  int b = idx >> 11;
  int s0 = sg * 4;
  int h6 = h * CHD;

  q_l[wv][l] = Q[((size_t)(b * CS + s0 + wv)) * CD + h6 + l];
  __syncthreads();

  float lmax[4] = {-1e30f, -1e30f, -1e30f, -1e30f};

  // ---- phase 1: scores. wave handles m in [wv*M/4, (wv+1)*M/4), groups of 512.
#pragma unroll 1
  for (int g = 0; g < NG; ++g) {
    int mg0 = wv * (M / 4) + g * 512;
    int mA = mg0 + 4 * l;
    int mB = mA + 256;
    float4 ipA = *(const float4*)&imp[mA];
    float4 ipB = *(const float4*)&imp[mB];
    float acc[8][4];
#pragma unroll
    for (int i = 0; i < 8; ++i)
#pragma unroll
      for (int q = 0; q < 4; ++q) acc[i][q] = 0.f;

#pragma unroll 2
    for (int c = 0; c < 16; ++c) {
      float4 qf0 = *(const float4*)&q_l[0][c * 4];
      float4 qf1 = *(const float4*)&q_l[1][c * 4];
      float4 qf2 = *(const float4*)&q_l[2][c * 4];
      float4 qf3 = *(const float4*)&q_l[3][c * 4];
      float qv[4][4];
      qv[0][0] = qf0.x; qv[0][1] = qf0.y; qv[0][2] = qf0.z; qv[0][3] = qf0.w;
      qv[1][0] = qf1.x; qv[1][1] = qf1.y; qv[1][2] = qf1.z; qv[1][3] = qf1.w;
      qv[2][0] = qf2.x; qv[2][1] = qf2.y; qv[2][2] = qf2.z; qv[2][3] = qf2.w;
      qv[3][0] = qf3.x; qv[3][1] = qf3.y; qv[3][2] = qf3.z; qv[3][3] = qf3.w;
#pragma unroll
      for (int dd = 0; dd < 4; ++dd) {
        const ushort_t* kp = KT + (size_t)(h6 + c * 4 + dd) * M + mA;
        uint2 ka = *(const uint2*)kp;
        uint2 kb = *(const uint2*)(kp + 256);
        float kA[4] = {u2f(ka.x << 16), u2f(ka.x & 0xFFFF0000u),
                       u2f(ka.y << 16), u2f(ka.y & 0xFFFF0000u)};
        float kB[4] = {u2f(kb.x << 16), u2f(kb.x & 0xFFFF0000u),
                       u2f(kb.y << 16), u2f(kb.y & 0xFFFF0000u)};
#pragma unroll
        for (int q = 0; q < 4; ++q) {
          float qq = qv[q][dd];
#pragma unroll
          for (int mi = 0; mi < 4; ++mi) {
            acc[mi][q] += kA[mi] * qq;
            acc[4 + mi][q] += kB[mi] * qq;
          }
        }
      }
    }
    // scale + bf16 store + max
#pragma unroll
    for (int q = 0; q < 4; ++q) {
      float sA0 = acc[0][q] * 0.125f * ipA.x;
      float sA1 = acc[1][q] * 0.125f * ipA.y;
      float sA2 = acc[2][q] * 0.125f * ipA.z;
      float sA3 = acc[3][q] * 0.125f * ipA.w;
      float sB0 = acc[4][q] * 0.125f * ipB.x;
      float sB1 = acc[5][q] * 0.125f * ipB.y;
      float sB2 = acc[6][q] * 0.125f * ipB.z;
      float sB3 = acc[7][q] * 0.125f * ipB.w;
      lmax[q] = fmaxf(lmax[q], fmaxf(fmaxf(sA0, sA1), fmaxf(sA2, sA3)));
      lmax[q] = fmaxf(lmax[q], fmaxf(fmaxf(sB0, sB1), fmaxf(sB2, sB3)));
      unsigned pA0 = (unsigned)f2bf(sA0) | ((unsigned)f2bf(sA1) << 16);
      unsigned pA1 = (unsigned)f2bf(sA2) | ((unsigned)f2bf(sA3) << 16);
      unsigned pB0 = (unsigned)f2bf(sB0) | ((unsigned)f2bf(sB1) << 16);
      unsigned pB1 = (unsigned)f2bf(sB2) | ((unsigned)f2bf(sB3) << 16);
      *(uint2*)&sc_l[q][mA] = make_uint2(pA0, pA1);
      *(uint2*)&sc_l[q][mB] = make_uint2(pB0, pB1);
    }
  }
  // per-wave max -> LDS
#pragma unroll
  for (int q = 0; q < 4; ++q) {
    float v = lmax[q];
#pragma unroll
    for (int off = 32; off > 0; off >>= 1) v = fmaxf(v, __shfl_down(v, off, 64));
    if (l == 0) wmax[wv][q] = v;
  }
  __syncthreads();

  // ---- phase 2: wave wv owns query wv. barrier-free from here. ----
  int w = wv;
  float t = fmaxf(fmaxf(wmax[0][w], wmax[1][w]), fmaxf(wmax[2][w], wmax[3][w]));

  // level-1 histogram (high 8 bits of mono16)
  *(int4*)&hist[w][4 * l] = make_int4(0, 0, 0, 0);
#pragma unroll 1
  for (int j = 0; j < M / 256; ++j) {
    uint2 sv = *(const uint2*)&sc_l[w][j * 256 + 4 * l];
    atomicAdd(&hist[w][mono16((ushort_t)(sv.x & 0xFFFF)) >> 8], 1);
    atomicAdd(&hist[w][mono16((ushort_t)(sv.x >> 16)) >> 8], 1);
    atomicAdd(&hist[w][mono16((ushort_t)(sv.y & 0xFFFF)) >> 8], 1);
    atomicAdd(&hist[w][mono16((ushort_t)(sv.y >> 16)) >> 8], 1);
  }
  int2 sel1 = wave_hist_select(hist[w], l, kth);
  int b1 = sel1.x, k1 = sel1.y;

  // level-2 histogram (low 8 bits, within bucket b1)
  *(int4*)&hist[w][4 * l] = make_int4(0, 0, 0, 0);
#pragma unroll 1
  for (int j = 0; j < M / 256; ++j) {
    uint2 sv = *(const uint2*)&sc_l[w][j * 256 + 4 * l];
    int m0 = mono16((ushort_t)(sv.x & 0xFFFF));
    int m1 = mono16((ushort_t)(sv.x >> 16));
    int m2 = mono16((ushort_t)(sv.y & 0xFFFF));
    int m3 = mono16((ushort_t)(sv.y >> 16));
    if ((m0 >> 8) == b1) atomicAdd(&hist[w][m0 & 0xFF], 1);
    if ((m1 >> 8) == b1) atomicAdd(&hist[w][m1 & 0xFF], 1);
    if ((m2 >> 8) == b1) atomicAdd(&hist[w][m2 & 0xFF], 1);
    if ((m3 >> 8) == b1) atomicAdd(&hist[w][m3 & 0xFF], 1);
  }
  int2 sel2 = wave_hist_select(hist[w], l, k1);
  int thr = (b1 << 8) | sel2.x;

  // compact + weight sum (ballot-based, no barriers)
  float ws = 0.f;
  int nsel = 0;
#pragma unroll 1
  for (int j = 0; j < M / 64; ++j) {
    int m = j * 64 + l;
    ushort_t u = sc_l[w][m];
    bool sel = mono16(u) >= thr;
    unsigned long long mask = __ballot(sel);
    if (sel) {
      int pos = nsel + __builtin_popcountll(mask & ((1ull << l) - 1ull));
      if (pos < LCAP) il[w][pos] = (ushort_t)m;
      ws += __expf(bf2f(u) - t);
    }
    nsel += __builtin_popcountll(mask);
  }
#pragma unroll
  for (int off = 32; off > 0; off >>= 1) ws += __shfl_down(ws, off, 64);
  float wsum = __shfl(ws, 0, 64);
  int n = nsel < LCAP ? nsel : LCAP;

  // ---- phase 3: PV over selected rows; lane = output dim ----
  {
    float wsc = scal[scal_idx] / wsum;
    const float* Vh = Vp + h6 + l;
    float acc = 0.f;
    int i = 0;
    for (; i + 4 <= n; i += 4) {
      int m0 = il[w][i], m1 = il[w][i + 1], m2 = il[w][i + 2], m3 = il[w][i + 3];
      float v0 = Vh[(size_t)m0 * CD];
      float v1 = Vh[(size_t)m1 * CD];
      float v2 = Vh[(size_t)m2 * CD];
      float v3 = Vh[(size_t)m3 * CD];
      float w0 = __expf(bf2f(sc_l[w][m0]) - t);
      float w1 = __expf(bf2f(sc_l[w][m1]) - t);
      float w2 = __expf(bf2f(sc_l[w][m2]) - t);
      float w3 = __expf(bf2f(sc_l[w][m3]) - t);
      acc += w0 * v0 + w1 * v1 + w2 * v2 + w3 * v3;
    }
    for (; i < n; ++i) {
      int m0 = il[w][i];
      acc += __expf(bf2f(sc_l[w][m0]) - t) * Vh[(size_t)m0 * CD];
    }
    size_t off = ((size_t)(b * CS + s0 + w)) * CD + h6 + l;
    float o = acc * wsc;
    if (add_to) mem_out[off] += o;
    else mem_out[off] = o;
  }
}

// ---------------- K2 v2 (fallback if ws too small): round-4 kernel ----------
template <int M, int NPT, int LCAP>
__global__ __launch_bounds__(256) void attn_v2(
    const float* __restrict__ Q, const float* __restrict__ Kp,
    const float* __restrict__ Vp, const float* __restrict__ imp,
    const float* __restrict__ scal, int scal_idx, int kth,
    float* __restrict__ mem_out, int add_to) {
  __shared__ float q_l[4][CHD];
  __shared__ ushort_t sc_l[4][M];
  __shared__ ushort_t il[4][LCAP];
  __shared__ int hist[256];
  __shared__ int hc[256];
  __shared__ float fscr[4];
  __shared__ int iscr[4];
  __shared__ int bsel, ksel;

  int tid = threadIdx.x;
  int idx = blockIdx.x;
  int sg = idx & (CS / 4 - 1);
  int h = (idx >> 7) & (CH - 1);
  int b = idx >> 11;
  int s0 = sg * 4;

  {
    int qi = tid >> 6, d = tid & 63;
    q_l[qi][d] = Q[((size_t)(b * CS + s0 + qi)) * CD + h * CHD + d];
  }
  __syncthreads();

  float lmax0 = -1e30f, lmax1 = -1e30f, lmax2 = -1e30f, lmax3 = -1e30f;
  for (int j0 = 0; j0 < NPT; j0 += 2) {
    int m0 = tid + j0 * 256;
    int m1 = m0 + 256;
    float a00 = 0, a01 = 0, a10 = 0, a11 = 0, a20 = 0, a21 = 0, a30 = 0, a31 = 0;
#pragma unroll
    for (int qt = 0; qt < 4; ++qt) {
      const float4* r0 = (const float4*)(Kp + (size_t)m0 * CD + h * CHD + qt * 16);
      const float4* r1 = (const float4*)(Kp + (size_t)m1 * CD + h * CHD + qt * 16);
      float4 kA[4], kB[4];
#pragma unroll
      for (int c = 0; c < 4; ++c) { kA[c] = r0[c]; kB[c] = r1[c]; }
#pragma unroll
      for (int c = 0; c < 4; ++c) {
        float4 q0 = *(const float4*)&q_l[0][qt * 16 + c * 4];
        float4 q1 = *(const float4*)&q_l[1][qt * 16 + c * 4];
        float4 q2 = *(const float4*)&q_l[2][qt * 16 + c * 4];
        float4 q3 = *(const float4*)&q_l[3][qt * 16 + c * 4];
        a00 += kA[c].x * q0.x + kA[c].y * q0.y + kA[c].z * q0.z + kA[c].w * q0.w;
        a01 += kB[c].x * q0.x + kB[c].y * q0.y + kB[c].z * q0.z + kB[c].w * q0.w;
        a10 += kA[c].x * q1.x + kA[c].y * q1.y + kA[c].z * q1.z + kA[c].w * q1.w;
        a11 += kB[c].x * q1.x + kB[c].y * q1.y + kB[c].z * q1.z + kB[c].w * q1.w;
        a20 += kA[c].x * q2.x + kA[c].y * q2.y + kA[c].z * q2.z + kA[c].w * q2.w;
        a21 += kB[c].x * q2.x + kB[c].y * q2.y + kB[c].z * q2.z + kB[c].w * q2.w;
        a30 += kA[c].x * q3.x + kA[c].y * q3.y + kA[c].z * q3.z + kA[c].w * q3.w;
        a31 += kB[c].x * q3.x + kB[c].y * q3.y + kB[c].z * q3.z + kB[c].w * q3.w;
      }
    }
    float f0 = 0.125f * imp[m0], f1 = 0.125f * imp[m1];
    float s00 = a00 * f0, s01 = a01 * f1;
    float s10 = a10 * f0, s11 = a11 * f1;
    float s20 = a20 * f0, s21 = a21 * f1;
    float s30 = a30 * f0, s31 = a31 * f1;
    sc_l[0][m0] = f2bf(s00); sc_l[0][m1] = f2bf(s01);
    sc_l[1][m0] = f2bf(s10); sc_l[1][m1] = f2bf(s11);
    sc_l[2][m0] = f2bf(s20); sc_l[2][m1] = f2bf(s21);
    sc_l[3][m0] = f2bf(s30); sc_l[3][m1] = f2bf(s31);
    lmax0 = fmaxf(lmax0, fmaxf(s00, s01));
    lmax1 = fmaxf(lmax1, fmaxf(s10, s11));
    lmax2 = fmaxf(lmax2, fmaxf(s20, s21));
    lmax3 = fmaxf(lmax3, fmaxf(s30, s31));
  }

  float gmaxr[4];
  gmaxr[0] = block_max_f(lmax0, fscr, tid);
  gmaxr[1] = block_max_f(lmax1, fscr, tid);
  gmaxr[2] = block_max_f(lmax2, fscr, tid);
  gmaxr[3] = block_max_f(lmax3, fscr, tid);

  float wsumr[4];
  int nselr[4];

  for (int qi = 0; qi < 4; ++qi) {
    hist[tid] = 0;
    __syncthreads();
#pragma unroll
    for (int j = 0; j < NPT; ++j) {
      ushort_t u = sc_l[qi][tid + j * 256];
      atomicAdd(&hist[mono16(u) >> 8], 1);
    }
    __syncthreads();
    hc[tid] = hist[tid];
    __syncthreads();
#pragma unroll
    for (int off = 1; off < 256; off <<= 1) {
      int add = (tid + off < 256) ? hc[tid + off] : 0;
      __syncthreads();
      hc[tid] += add;
      __syncthreads();
    }
    if (hc[tid] >= kth && (tid == 255 || hc[tid + 1] < kth)) {
      bsel = tid;
      ksel = kth - (tid == 255 ? 0 : hc[tid + 1]);
    }
    __syncthreads();
    int b1 = bsel, kp = ksel;
    __syncthreads();
    hist[tid] = 0;
    __syncthreads();
#pragma unroll
    for (int j = 0; j < NPT; ++j) {
      int mn = mono16(sc_l[qi][tid + j * 256]);
      if ((mn >> 8) == b1) atomicAdd(&hist[mn & 0xFF], 1);
    }
    __syncthreads();
    hc[tid] = hist[tid];
    __syncthreads();
#pragma unroll
    for (int off = 1; off < 256; off <<= 1) {
      int add = (tid + off < 256) ? hc[tid + off] : 0;
      __syncthreads();
      hc[tid] += add;
      __syncthreads();
    }
    if (hc[tid] >= kp && (tid == 255 || hc[tid + 1] < kp)) bsel = tid;
    __syncthreads();
    int thr = (b1 << 8) | bsel;
    __syncthreads();

    float gm = gmaxr[qi];
    int cnt = 0;
    float ws = 0.f;
#pragma unroll
    for (int j = 0; j < NPT; ++j) {
      ushort_t u = sc_l[qi][tid + j * 256];
      if (mono16(u) >= thr) {
        cnt++;
        ws += __expf(bf2f(u) - gm);
      }
    }
    int lane = tid & 63, wv = tid >> 6;
    int v = cnt;
#pragma unroll
    for (int off = 1; off < 64; off <<= 1) {
      int tt = __shfl_up(v, off, 64);
      if (lane >= off) v += tt;
    }
    if (lane == 63) iscr[wv] = v;
    __syncthreads();
    int base = 0;
#pragma unroll
    for (int ww = 0; ww < 4; ++ww)
      if (ww < wv) base += iscr[ww];
    int pos = base + v - cnt;
    int ntot = iscr[0] + iscr[1] + iscr[2] + iscr[3];
    __syncthreads();
#pragma unroll
    for (int j = 0; j < NPT; ++j) {
      int m = tid + j * 256;
      ushort_t u = sc_l[qi][m];
      if (mono16(u) >= thr) {
        if (pos < LCAP) il[qi][pos] = (ushort_t)m;
        pos++;
      }
    }
    wsumr[qi] = block_sum_f(ws, fscr, tid);
    nselr[qi] = ntot < LCAP ? ntot : LCAP;
    __syncthreads();
  }

  {
    int wv = tid >> 6, d = tid & 63;
    float gm = gmaxr[wv];
    float wsc = scal[scal_idx] / wsumr[wv];
    int n = nselr[wv];
    const float* Vh = Vp + h * CHD + d;
    float acc = 0.f;
    int i = 0;
    for (; i + 4 <= n; i += 4) {
      int m0 = il[wv][i], m1 = il[wv][i + 1], m2 = il[wv][i + 2], m3 = il[wv][i + 3];
      float v0 = Vh[(size_t)m0 * CD];
      float v1 = Vh[(size_t)m1 * CD];
      float v2 = Vh[(size_t)m2 * CD];
      float v3 = Vh[(size_t)m3 * CD];
      float w0 = __expf(bf2f(sc_l[wv][m0]) - gm);
      float w1 = __expf(bf2f(sc_l[wv][m1]) - gm);
      float w2 = __expf(bf2f(sc_l[wv][m2]) - gm);
      float w3 = __expf(bf2f(sc_l[wv][m3]) - gm);
      acc += w0 * v0 + w1 * v1 + w2 * v2 + w3 * v3;
    }
    for (; i < n; ++i) {
      int m0 = il[wv][i];
      acc += __expf(bf2f(sc_l[wv][m0]) - gm) * Vh[(size_t)m0 * CD];
    }
    size_t off = ((size_t)(b * CS + s0 + wv)) * CD + h * CHD + d;
    float o = acc * wsc;
    if (add_to) mem_out[off] += o;
    else mem_out[off] = o;
  }
}

// ---------------- K3: gate + residual + LayerNorm ----------------
__global__ __launch_bounds__(256) void gate_ln_kernel(
    const float* __restrict__ X, const float* __restrict__ Mem,
    const float* __restrict__ Wg, const float* __restrict__ bg,
    const float* __restrict__ lng, const float* __restrict__ lnb,
    float* __restrict__ Out) {
  __shared__ float scr[4];
  int tid = threadIdx.x;
  int row = blockIdx.x;
  int d0 = tid * 4;

  float4 px = *(const float4*)(X + (size_t)row * CD + d0);
  float4 pm = *(const float4*)(Mem + (size_t)row * CD + d0);
  float4 wi = *(const float4*)(Wg + d0);
  float4 wm = *(const float4*)(Wg + CD + d0);

  float t = px.x * wi.x + px.y * wi.y + px.z * wi.z + px.w * wi.w +
            pm.x * wm.x + pm.y * wm.y + pm.z * wm.z + pm.w * wm.w;
  float z = block_sum_f(t, scr, tid) + bg[0];
  float gate = 1.f / (1.f + __expf(-z));

  float xr0 = px.x + pm.x * gate;
  float xr1 = px.y + pm.y * gate;
  float xr2 = px.z + pm.z * gate;
  float xr3 = px.w + pm.w * gate;

  float ssum = block_sum_f(xr0 + xr1 + xr2 + xr3, scr, tid);
  float ssq = block_sum_f(xr0 * xr0 + xr1 * xr1 + xr2 * xr2 + xr3 * xr3, scr, tid);
  float mu = ssum * (1.f / CD);
  float var = ssq * (1.f / CD) - mu * mu;
  float inv = rsqrtf(var + 1e-5f);

  float4 pg = *(const float4*)(lng + d0);
  float4 pb = *(const float4*)(lnb + d0);
  float4 o;
  o.x = (xr0 - mu) * inv * pg.x + pb.x;
  o.y = (xr1 - mu) * inv * pg.y + pb.y;
  o.z = (xr2 - mu) * inv * pg.z + pb.z;
  o.w = (xr3 - mu) * inv * pg.w + pb.w;
  *(float4*)(Out + (size_t)row * CD + d0) = o;
}

extern "C" void kernel_launch(void* const* d_in, const int* in_sizes, int n_in,
                              void* d_out, int out_size, void* d_ws, size_t ws_size,
                              hipStream_t stream) {
  const float* inputs = (const float*)d_in[0];
  const float* Wq = (const float*)d_in[1];
  const float* bq = (const float*)d_in[2];
  const float* st_keys = (const float*)d_in[3];
  const float* st_values = (const float*)d_in[4];
  const float* lt_keys = (const float*)d_in[5];
  const float* lt_values = (const float*)d_in[6];
  const float* st_imp = (const float*)d_in[7];
  const float* lt_imp = (const float*)d_in[8];
  const float* Wg = (const float*)d_in[9];
  const float* bg = (const float*)d_in[10];
  const float* ln_g = (const float*)d_in[11];
  const float* ln_b = (const float*)d_in[12];
  float* out = (float*)d_out;

  size_t nQ = (size_t)CB * CS * CD;
  float* Qws = (float*)d_ws;
  float* Memws = Qws + nQ;
  float* scal = Memws + nQ;
  ushort_t* KTst = (ushort_t*)(scal + 64);
  ushort_t* KTlt = KTst + (size_t)CD * CST;
  size_t need = (size_t)((char*)(KTlt + (size_t)CD * CLT) - (char*)d_ws);

  int nblk = CB * CH * (CS / 4);  // 4096

  prep_kernel<<<1, 256, 0, stream>>>(st_imp, lt_imp, scal);
  qproj_kernel<<<CB * CS / 4, 256, 0, stream>>>(inputs, Wq, bq, Qws);

  if (ws_size >= need) {
    ktrans_kernel<CST><<<(CST / 64) * CH, 256, 0, stream>>>(st_keys, KTst);
    ktrans_kernel<CLT><<<(CLT / 64) * CH, 256, 0, stream>>>(lt_keys, KTlt);
    attn_v3<CST, 512, 1><<<nblk, 256, 0, stream>>>(
        Qws, KTst, st_values, st_imp, scal, 0, CKST, Memws, 0);
    attn_v3<CLT, 1024, 3><<<nblk, 256, 0, stream>>>(
        Qws, KTlt, lt_values, lt_imp, scal, 1, CKLT, Memws, 1);
  } else {
    attn_v2<CST, CST / 256, 512><<<nblk, 256, 0, stream>>>(
        Qws, st_keys, st_values, st_imp, scal, 0, CKST, Memws, 0);
    attn_v2<CLT, CLT / 256, 1024><<<nblk, 256, 0, stream>>>(
        Qws, lt_keys, lt_values, lt_imp, scal, 1, CKLT, Memws, 1);
  }
  gate_ln_kernel<<<CB * CS, 256, 0, stream>>>(inputs, Memws, Wg, bg, ln_g, ln_b, out);
}